// Round 1
// baseline (742.352 us; speedup 1.0000x reference)
//
#include <hip/hip_runtime.h>
#include <hip/hip_cooperative_groups.h>

namespace cg = cooperative_groups;

#define N     512
#define NSP   4          // column stripes per sample
#define SC    128        // columns per stripe
#define EPS   1e-4f

// ---- fallback (previous pipeline) LDS layout ----
#define MROW  65
#define LDS_U   (512 * MROW + 512 + 128 * 33 + 128 + 64)
#define LDS_BYTES (LDS_U * 4)

// ---- f16 helpers ----
union U32H { unsigned int u; _Float16 h[2]; };
__device__ inline float h_lo(unsigned int x){ U32H t; t.u = x; return (float)t.h[0]; }
__device__ inline float h_hi(unsigned int x){ U32H t; t.u = x; return (float)t.h[1]; }
__device__ inline unsigned int h_pk(float a, float b){ U32H t; t.h[0]=(_Float16)a; t.h[1]=(_Float16)b; return t.u; }

typedef _Float16 half2v __attribute__((ext_vector_type(2)));
#if __has_builtin(__builtin_amdgcn_fdot2)
__device__ inline float dot2(unsigned int m, unsigned int v, float c){
    return __builtin_amdgcn_fdot2(__builtin_bit_cast(half2v, m), __builtin_bit_cast(half2v, v), c, false);
}
#else
__device__ inline float dot2(unsigned int m, unsigned int v, float c){
    return c + h_lo(m)*h_lo(v) + h_hi(m)*h_hi(v);
}
#endif

// ============================================================================
// Fused cooperative kernel: matrix register-resident, 10 iterations, 5 syncs.
// Block (sp,b): 128-col stripe of sample b, all 512 rows.
// Thread (w,rg,j): rows it*32 + (w*4+rg), it=0..15; cols c0+8j .. c0+8j+7.
// Sinkhorn identity: v_{t+1} = 1/(e^T u_t), u_{t+1} = 1/(e v_{t+1}) — only
// the LATEST u,v are needed (cumulative scales cancel). out = e * u9 ⊗ v8.
// ============================================================================

// col-sum reduce across the 32 row-partitions -> vf (1/colsum), vpk (f16 pairs)
__device__ inline void col_reduce(float* red, float* vf, unsigned int* vpk,
                                  const float acc[8], int t, int part, int j,
                                  int c0, int n) {
#pragma unroll
    for (int k = 0; k < 8; ++k) red[(8*j + k)*33 + part] = acc[k];
    __syncthreads();
    if (t < 128) {
        float s = 0.f;
#pragma unroll
        for (int p = 0; p < 32; ++p) s += red[t*33 + p];
        vf[t] = (c0 + t < n) ? 1.f / s : 0.f;
    }
    __syncthreads();
    if (t < 64) vpk[t] = h_pk(vf[2*t], vf[2*t+1]);
    __syncthreads();
}

// row partials from register-resident m: rp[it] = sum_c m[it][c]*v[c], then
// reduce-scatter across the 16 j-lanes (lane j ends with row it=j's total).
__device__ inline void row_part(const unsigned int m[16][4], const unsigned int* vpk,
                                int j, int part, float* __restrict__ rp_dst) {
    const unsigned int vp0 = vpk[4*j+0], vp1 = vpk[4*j+1];
    const unsigned int vp2 = vpk[4*j+2], vp3 = vpk[4*j+3];
    float rp[16];
#pragma unroll
    for (int it = 0; it < 16; ++it) {
        float p = dot2(m[it][0], vp0, 0.f);
        p = dot2(m[it][1], vp1, p);
        p = dot2(m[it][2], vp2, p);
        p = dot2(m[it][3], vp3, p);
        rp[it] = p;
    }
    // reduce-scatter over j within each 16-lane group: 15 shuffles total
#pragma unroll
    for (int d = 8; d >= 1; d >>= 1) {
        const bool up = (j & d) != 0;
#pragma unroll
        for (int i = 0; i < d; ++i) {
            float send = up ? rp[i] : rp[i + d];
            float got  = __shfl_xor(send, d, 16);
            rp[i] = (up ? rp[i + d] : rp[i]) + got;
        }
    }
    rp_dst[j*32 + part] = rp[0];
}

__global__ __launch_bounds__(512, 4)
void k_fused(const float* __restrict__ A, const int* __restrict__ nrows,
             float* __restrict__ rpA, float* __restrict__ rpB,
             float* __restrict__ out) {
    __shared__ float red[128*33];
    __shared__ float uu[512];
    __shared__ float vf[128];
    __shared__ unsigned int vpk[64];

    const int b = blockIdx.y, sp = blockIdx.x, c0 = sp * SC;
    const int n = nrows[b];
    const int t = threadIdx.x;
    const int l = t & 63;
    const int j = l & 15;
    const int part = (t >> 6) * 4 + (l >> 4);   // 0..31
    const size_t baseA = (size_t)b * N * N;
    const int cb = c0 + 8*j;
    const size_t rpOff = ((size_t)b * NSP + sp) * N;
    const size_t rpB0  = (size_t)b * NSP * N;
    cg::grid_group grid = cg::this_grid();

    bool cok[8];
#pragma unroll
    for (int k = 0; k < 8; ++k) cok[k] = (cb + k) < n;

    // ---- load A once -> masked f16 in registers; pass-0 col sums (u == 1) ----
    unsigned int m[16][4];
    {
        float acc[8] = {0,0,0,0,0,0,0,0};
#pragma unroll
        for (int it = 0; it < 16; ++it) {
            const int r = it*32 + part;
            const float4* p = (const float4*)(A + baseA + (size_t)r*N + cb);
            float4 a0 = p[0], a1 = p[1];
            const bool rok = r < n;
            float e[8];
            e[0] = (rok & cok[0]) ? a0.x + EPS : 0.f;
            e[1] = (rok & cok[1]) ? a0.y + EPS : 0.f;
            e[2] = (rok & cok[2]) ? a0.z + EPS : 0.f;
            e[3] = (rok & cok[3]) ? a0.w + EPS : 0.f;
            e[4] = (rok & cok[4]) ? a1.x + EPS : 0.f;
            e[5] = (rok & cok[5]) ? a1.y + EPS : 0.f;
            e[6] = (rok & cok[6]) ? a1.z + EPS : 0.f;
            e[7] = (rok & cok[7]) ? a1.w + EPS : 0.f;
#pragma unroll
            for (int k = 0; k < 8; ++k) acc[k] += e[k];
            m[it][0] = h_pk(e[0], e[1]);
            m[it][1] = h_pk(e[2], e[3]);
            m[it][2] = h_pk(e[4], e[5]);
            m[it][3] = h_pk(e[6], e[7]);
        }
        col_reduce(red, vf, vpk, acc, t, part, j, c0, n);   // v0
    }
    row_part(m, vpk, j, part, rpA + rpOff);                  // rp1
    grid.sync();

    // ---- passes 1..4: u = 1/sum(rp), col-normalize, next row partials ----
    auto do_pass = [&](const float* __restrict__ rIn, float* __restrict__ rOut) {
        {
            float s = rIn[rpB0 + 0*N + t] + rIn[rpB0 + 1*N + t]
                    + rIn[rpB0 + 2*N + t] + rIn[rpB0 + 3*N + t];
            uu[t] = (t < n) ? 1.f / s : 0.f;
        }
        __syncthreads();
        float acc[8] = {0,0,0,0,0,0,0,0};
#pragma unroll
        for (int it = 0; it < 16; ++it) {
            const float ur = uu[it*32 + part];
            acc[0] += ur * h_lo(m[it][0]);
            acc[1] += ur * h_hi(m[it][0]);
            acc[2] += ur * h_lo(m[it][1]);
            acc[3] += ur * h_hi(m[it][1]);
            acc[4] += ur * h_lo(m[it][2]);
            acc[5] += ur * h_hi(m[it][2]);
            acc[6] += ur * h_lo(m[it][3]);
            acc[7] += ur * h_hi(m[it][3]);
        }
        col_reduce(red, vf, vpk, acc, t, part, j, c0, n);
        row_part(m, vpk, j, part, rOut + rpOff);
        grid.sync();
    };
    do_pass(rpA, rpB);   // u1, v2, rp3
    do_pass(rpB, rpA);   // u3, v4, rp5
    do_pass(rpA, rpB);   // u5, v6, rp7
    do_pass(rpB, rpA);   // u7, v8, rp9  (rp9 -> rpA; vf holds v8)

    // ---- epilogue from registers: out = m * u9[r] * v8[c] ----
    {
        float s = rpA[rpB0 + 0*N + t] + rpA[rpB0 + 1*N + t]
                + rpA[rpB0 + 2*N + t] + rpA[rpB0 + 3*N + t];
        uu[t] = (t < n) ? 1.f / s : 0.f;
    }
    __syncthreads();
    const float v0 = vf[8*j+0], v1 = vf[8*j+1], v2 = vf[8*j+2], v3 = vf[8*j+3];
    const float v4 = vf[8*j+4], v5 = vf[8*j+5], v6 = vf[8*j+6], v7 = vf[8*j+7];
#pragma unroll
    for (int it = 0; it < 16; ++it) {
        const int r = it*32 + part;
        const float ur = uu[r];
        float4 o0, o1;
        o0.x = h_lo(m[it][0]) * ur * v0;
        o0.y = h_hi(m[it][0]) * ur * v1;
        o0.z = h_lo(m[it][1]) * ur * v2;
        o0.w = h_hi(m[it][1]) * ur * v3;
        o1.x = h_lo(m[it][2]) * ur * v4;
        o1.y = h_hi(m[it][2]) * ur * v5;
        o1.z = h_lo(m[it][3]) * ur * v6;
        o1.w = h_hi(m[it][3]) * ur * v7;
        float4* q = (float4*)(out + baseA + (size_t)r*N + cb);
        q[0] = o0; q[1] = o1;
    }
}

// ============================================================================
// Fallback: previous verified 6-kernel pipeline (used only if the cooperative
// launch is rejected by the runtime/capture).
// ============================================================================

__device__ inline void pass_tail(unsigned int* M2, float* red, float* vf, unsigned int* vpk,
                                 const float acc[8], int t, int part, int j, int c0, int n,
                                 int b, int sp, float* __restrict__ rp_out,
                                 float* __restrict__ vf_out) {
#pragma unroll
    for (int k = 0; k < 8; ++k) red[(8*j + k)*33 + part] = acc[k];
    __syncthreads();
    if (t < 128) {
        float s = 0.f;
#pragma unroll
        for (int p = 0; p < 32; ++p) s += red[t*33 + p];
        float v = (c0 + t < n) ? 1.f / s : 0.f;
        vf[t] = v;
        if (vf_out) vf_out[b*N + c0 + t] = v;
    }
    __syncthreads();
    if (t < 64) vpk[t] = h_pk(vf[2*t], vf[2*t+1]);
    __syncthreads();
    float p = 0.f;
    const unsigned int* row = M2 + t * MROW;
#pragma unroll
    for (int q = 0; q < 64; ++q) p = dot2(row[q], vpk[q], p);
    rp_out[((size_t)b*NSP + sp)*N + t] = p;
}

__global__ __launch_bounds__(512)
void k_pass0(const float* __restrict__ A, const int* __restrict__ nrows,
             unsigned int* __restrict__ Abf, float* __restrict__ rp_out) {
    extern __shared__ unsigned int lds[];
    unsigned int* M2 = lds;
    float* uu = (float*)(lds + 512*MROW);
    float* red = uu + 512;
    float* vf  = red + 128*33;
    unsigned int* vpk = (unsigned int*)(vf + 128);

    const int b = blockIdx.y, sp = blockIdx.x, c0 = sp * SC;
    const int n = nrows[b];
    const int t = threadIdx.x;
    const int w = t >> 6, l = t & 63;
    const int j = l & 15, rg = l >> 4;
    const size_t baseA = (size_t)b * N * N;
    const size_t baseH = (size_t)b * N * (N/2);
    const int cb = c0 + 8*j;

    bool cok[8];
#pragma unroll
    for (int k = 0; k < 8; ++k) cok[k] = (cb + k) < n;

    float acc[8] = {0,0,0,0,0,0,0,0};
    for (int it = 0; it < 16; ++it) {
        int r = it*32 + w*4 + rg;
        const float4* p = (const float4*)(A + baseA + (size_t)r*N + cb);
        float4 a0 = p[0], a1 = p[1];
        bool rok = r < n;
        float e[8];
        e[0] = (rok && cok[0]) ? a0.x + EPS : 0.f;
        e[1] = (rok && cok[1]) ? a0.y + EPS : 0.f;
        e[2] = (rok && cok[2]) ? a0.z + EPS : 0.f;
        e[3] = (rok && cok[3]) ? a0.w + EPS : 0.f;
        e[4] = (rok && cok[4]) ? a1.x + EPS : 0.f;
        e[5] = (rok && cok[5]) ? a1.y + EPS : 0.f;
        e[6] = (rok && cok[6]) ? a1.z + EPS : 0.f;
        e[7] = (rok && cok[7]) ? a1.w + EPS : 0.f;
#pragma unroll
        for (int k = 0; k < 8; ++k) acc[k] += e[k];
        uint4 q;
        q.x = h_pk(e[0], e[1]); q.y = h_pk(e[2], e[3]);
        q.z = h_pk(e[4], e[5]); q.w = h_pk(e[6], e[7]);
        *(uint4*)(Abf + baseH + (size_t)r*(N/2) + c0/2 + 4*j) = q;
        unsigned int* dst = M2 + r*MROW + 4*j;
        dst[0] = q.x; dst[1] = q.y; dst[2] = q.z; dst[3] = q.w;
    }
    (void)uu;
    pass_tail(M2, red, vf, vpk, acc, t, w*4 + rg, j, c0, n, b, sp, rp_out, nullptr);
}

__global__ __launch_bounds__(512)
void k_passN(const unsigned int* __restrict__ Abf, const int* __restrict__ nrows,
             const float* __restrict__ rp_in, float* __restrict__ rp_out,
             float* __restrict__ vf_out) {
    extern __shared__ unsigned int lds[];
    unsigned int* M2 = lds;
    float* uu = (float*)(lds + 512*MROW);
    float* red = uu + 512;
    float* vf  = red + 128*33;
    unsigned int* vpk = (unsigned int*)(vf + 128);

    const int b = blockIdx.y, sp = blockIdx.x, c0 = sp * SC;
    const int n = nrows[b];
    const int t = threadIdx.x;
    const int w = t >> 6, l = t & 63;
    const int j = l & 15, rg = l >> 4;
    const size_t baseH = (size_t)b * N * (N/2);

    {
        float s = rp_in[((size_t)b*NSP + 0)*N + t]
                + rp_in[((size_t)b*NSP + 1)*N + t]
                + rp_in[((size_t)b*NSP + 2)*N + t]
                + rp_in[((size_t)b*NSP + 3)*N + t];
        uu[t] = (t < n) ? 1.f / s : 0.f;
    }
    __syncthreads();

    float acc[8] = {0,0,0,0,0,0,0,0};
    for (int it = 0; it < 16; ++it) {
        int r = it*32 + w*4 + rg;
        uint4 q = *(const uint4*)(Abf + baseH + (size_t)r*(N/2) + c0/2 + 4*j);
        float ur = uu[r];
        acc[0] += ur * h_lo(q.x); acc[1] += ur * h_hi(q.x);
        acc[2] += ur * h_lo(q.y); acc[3] += ur * h_hi(q.y);
        acc[4] += ur * h_lo(q.z); acc[5] += ur * h_hi(q.z);
        acc[6] += ur * h_lo(q.w); acc[7] += ur * h_hi(q.w);
        unsigned int* dst = M2 + r*MROW + 4*j;
        dst[0] = q.x; dst[1] = q.y; dst[2] = q.z; dst[3] = q.w;
    }
    __syncthreads();
    pass_tail(M2, red, vf, vpk, acc, t, w*4 + rg, j, c0, n, b, sp, rp_out, vf_out);
}

__global__ __launch_bounds__(512)
void k_epi(const float* __restrict__ A, const int* __restrict__ nrows,
           const float* __restrict__ rp9, const float* __restrict__ vf8,
           float* __restrict__ out) {
    const int b = blockIdx.y;
    const int n = nrows[b];
    const int t = threadIdx.x;
    const int r = blockIdx.x*4 + (t >> 7);
    const int c = (t & 127) * 4;
    float s = rp9[((size_t)b*NSP + 0)*N + r]
            + rp9[((size_t)b*NSP + 1)*N + r]
            + rp9[((size_t)b*NSP + 2)*N + r]
            + rp9[((size_t)b*NSP + 3)*N + r];
    float ur = (r < n) ? 1.f / s : 0.f;
    float4 v = *(const float4*)(vf8 + b*N + c);
    const size_t off = (size_t)b*N*N + (size_t)r*N + c;
    float4 a = *(const float4*)(A + off);
    float4 o;
    o.x = (a.x + EPS) * ur * v.x;
    o.y = (a.y + EPS) * ur * v.y;
    o.z = (a.z + EPS) * ur * v.z;
    o.w = (a.w + EPS) * ur * v.w;
    *(float4*)(out + off) = o;
}

extern "C" void kernel_launch(void* const* d_in, const int* in_sizes, int n_in,
                              void* d_out, int out_size, void* d_ws, size_t ws_size,
                              hipStream_t stream) {
    const float* A     = (const float*)d_in[0];
    const int*   nrows = (const int*)d_in[1];
    float*       out   = (float*)d_out;
    const int    B     = in_sizes[1];   // 128

    float* rpA = (float*)d_ws;
    float* rpB = rpA + (size_t)B * NSP * N;
    float* vf8 = rpB + (size_t)B * NSP * N;

    // ---- preferred path: single cooperative kernel, 2 blocks/CU resident ----
    {
        void* args[] = { (void*)&A, (void*)&nrows, (void*)&rpA, (void*)&rpB, (void*)&out };
        hipError_t err = hipLaunchCooperativeKernel(
            reinterpret_cast<const void*>(&k_fused),
            dim3(NSP, B), dim3(512), args, 0, stream);
        if (err == hipSuccess) return;
    }

    // ---- fallback: previous verified multi-kernel pipeline ----
    size_t head = ((size_t)2*B*NSP*N + (size_t)B*N) * sizeof(float);
    size_t abf_bytes = (size_t)B * N * (N/2) * sizeof(unsigned int);
    unsigned int* Abf = (ws_size >= head + abf_bytes)
                      ? (unsigned int*)((char*)d_ws + head)
                      : (unsigned int*)d_out;

    hipFuncSetAttribute(reinterpret_cast<const void*>(k_pass0),
                        hipFuncAttributeMaxDynamicSharedMemorySize, LDS_BYTES);
    hipFuncSetAttribute(reinterpret_cast<const void*>(k_passN),
                        hipFuncAttributeMaxDynamicSharedMemorySize, LDS_BYTES);

    dim3 g(NSP, B);
    k_pass0<<<g, 512, LDS_BYTES, stream>>>(A, nrows, Abf, rpA);
    k_passN<<<g, 512, LDS_BYTES, stream>>>(Abf, nrows, rpA, rpB, nullptr);
    k_passN<<<g, 512, LDS_BYTES, stream>>>(Abf, nrows, rpB, rpA, nullptr);
    k_passN<<<g, 512, LDS_BYTES, stream>>>(Abf, nrows, rpA, rpB, nullptr);
    k_passN<<<g, 512, LDS_BYTES, stream>>>(Abf, nrows, rpB, rpA, vf8);
    k_epi<<<dim3(N/4, B), 512, 0, stream>>>(A, nrows, rpA, vf8, out);
}